// Round 8
// baseline (952.389 us; speedup 1.0000x reference)
//
#include <hip/hip_runtime.h>
#include <cstdint>
#include <cstddef>

typedef float v4f __attribute__((ext_vector_type(4)));
typedef short short8 __attribute__((ext_vector_type(8)));

constexpr int B_ = 8, P_ = 16384, Q_ = 256, E_ = 128;

// ---------- helpers ----------
__device__ __forceinline__ unsigned int f2bf(float f) {
  unsigned int x = __float_as_uint(f);
  x += 0x7FFFu + ((x >> 16) & 1u);           // round-to-nearest-even
  return x >> 16;
}
__device__ __forceinline__ float softplus_f(float x) {
  return fmaxf(x, 0.f) + __logf(1.f + __expf(-fabsf(x)));
}
__device__ __forceinline__ float wsum(float v) {
#pragma unroll
  for (int o = 32; o; o >>= 1) v += __shfl_xor(v, o, 64);
  return v;
}
// LDS-only barrier (no vmcnt drain); proven correct in R1/R5.
__device__ __forceinline__ void lds_barrier() {
  asm volatile("s_waitcnt lgkmcnt(0)" ::: "memory");
  __builtin_amdgcn_s_barrier();
}

// ---------- fused: prep + both GEMMs, split-K, e-split ----------
// R6/R7 lessons: (1) per-SIMD reg pool 512 -> 4 waves/SIMD needs <=128
// regs/wave -> acc must be 64 f/thread; (2) memory streams 2.4-4 TB/s when
// demand exists -- the lockstep single block only reaches ~28% duty.
// R8: TWO independent 8-wave blocks per CU (grid 512 = 2eh x 8b x 32ks),
// de-phased barriers overlap one block's memory burst with the other's
// compute. Block output = 256q x 64e x 2 (acc 64/thread). 16 p-rows/iter
// (2 rows/wave) -> prefetch only 18 regs; no spill at launch_bounds(512,4).
// eh = blockIdx>>8 so paired e-half blocks share an XCD -> duplicated
// mlv/mask stream is an L2 hit, not extra HBM.
// LDS: q-major pitch-8 rows (16B-aligned), 1-bit XOR swizzle; frag read =
// one ds_read_b128 (quads 0-1), literal zero for quads 2-3 (K=16 zero-pad,
// proven R7). negsum/ppsum atomics gated to eh==0 (A-side work duplicated).
template<bool DIRECT>
__global__ __launch_bounds__(512, 4) void fused_all(
    const float* __restrict__ mlv, const int* __restrict__ mask,
    const float* __restrict__ seg, float* __restrict__ part,
    float* __restrict__ negsum, float* __restrict__ ppsum,
    float* __restrict__ segsum, float* __restrict__ nnzb)
{
  __shared__ __align__(16) unsigned int lds[5120];   // 20480 B
  unsigned int* A1 = lds;            // 256q x 8 kpair-words
  unsigned int* EZ = lds + 2048;
  unsigned int* SB = lds + 4096;     // 64e x 8
  unsigned int* ST = lds + 4608;

  const int t = threadIdx.x, w = t >> 6, l = t & 63;
  const int lm = l & 15, quad = l >> 4;
  const int wr = w & 3, wc = w >> 2;            // q-block(64) / e-block(32)
  const int eh = blockIdx.x >> 8;               // e-half; pair shares XCD
  const int b  = (blockIdx.x >> 5) & 7;
  const int ks = blockIdx.x & 31;
  const int wx   = w ^ ((l & 1) << 2);          // swizzled write word
  const int qsel = 4 * (quad ^ (lm & 1));       // swizzled read block base
  const bool hasd = (quad < 2);                 // quads 2-3 = zero (K=16 pad)

  v4f acc0[4][2], acc1[4][2];
#pragma unroll
  for (int i = 0; i < 4; ++i)
#pragma unroll
    for (int j = 0; j < 2; ++j) { acc0[i][j] = (v4f)0.f; acc1[i][j] = (v4f)0.f; }
  float accN[4] = {0.f,0.f,0.f,0.f};
  float accP[4] = {0.f,0.f,0.f,0.f};
  float accS = 0.f, cnt = 0.f;

  // wave w owns p-rows {2w, 2w+1} of each 16-row step; q = l + 64j
  const float* mp = mlv + ((size_t)b * P_ + ks * 512 + 2 * w) * Q_ + l;
  const int*   kp = mask + ((size_t)b * P_ + ks * 512 + 2 * w) * Q_ + l;
  const float* sp = seg + ((size_t)b * P_ + ks * 512 + 2 * w) * E_ + eh * 64 + l;

  float X0[4], X1[4]; int M0[4], M1[4]; float S0, S1;
#pragma unroll
  for (int j = 0; j < 4; ++j) {
    X0[j] = mp[64 * j]; X1[j] = mp[Q_ + 64 * j];
    M0[j] = kp[64 * j]; M1[j] = kp[Q_ + 64 * j];
  }
  S0 = sp[0]; S1 = sp[E_];

  for (int it = 0; it < 32; ++it) {
    // ---- consume prefetched rows: softmax pieces + packing ----
    float ez0[4], ez1[4]; unsigned a1w[4];
    float s0 = 0.f, s1 = 0.f;
#pragma unroll
    for (int j = 0; j < 4; ++j) {
      const bool m0 = M0[j] != 0, m1 = M1[j] != 0;
      a1w[j] = f2bf(m0 ? -X0[j] : 0.f) | (f2bf(m1 ? -X1[j] : 0.f) << 16);
      const float e0 = m0 ? __expf(X0[j]) : 0.f;
      const float e1 = m1 ? __expf(X1[j]) : 0.f;
      ez0[j] = e0; ez1[j] = e1; s0 += e0; s1 += e1;
      accN[j] += __logf(1.f + e0) + __logf(1.f + e1);   // softplus on masked
    }
    const unsigned sbw = ((S0 > 0.f) ? 0x3F80u : 0u) | ((S1 > 0.f) ? 0x3F800000u : 0u);
    const unsigned stw = f2bf(S0) | (f2bf(S1) << 16);
    accS += S0 + S1;
    cnt  += ((S0 > 0.f) ? 1.f : 0.f) + ((S1 > 0.f) ? 1.f : 0.f);

    // ---- prefetch next step (in flight across both barriers) ----
    if (it < 31) {
      mp += 16 * Q_; kp += 16 * Q_; sp += 16 * E_;
#pragma unroll
      for (int j = 0; j < 4; ++j) {
        X0[j] = mp[64 * j]; X1[j] = mp[Q_ + 64 * j];
        M0[j] = kp[64 * j]; M1[j] = kp[Q_ + 64 * j];
      }
      S0 = sp[0]; S1 = sp[E_];
    }

    // ---- row sums (wave-local butterfly) + P pack ----
    s0 = wsum(s0); s1 = wsum(s1);
    const float i0 = (s0 > 0.f) ? (1.f / s0) : 0.f;
    const float i1 = (s1 > 0.f) ? (1.f / s1) : 0.f;
    unsigned ezw[4];
#pragma unroll
    for (int j = 0; j < 4; ++j) {
      const float p0 = ez0[j] * i0, p1 = ez1[j] * i1;
      accP[j] += p0 + p1;
      ezw[j] = f2bf(p0) | (f2bf(p1) << 16);
    }

    lds_barrier();   // previous MFMA phase done reading LDS
#pragma unroll
    for (int j = 0; j < 4; ++j) {
      A1[8 * l + 512 * j + wx] = a1w[j];
      EZ[8 * l + 512 * j + wx] = ezw[j];
    }
    SB[8 * l + wx] = sbw;
    ST[8 * l + wx] = stw;
    lds_barrier();   // writes visible to all waves

    // ---- MFMA phase: K=16 effective (quads 2-3 zero), b128 frag reads ----
    const short8 z8 = {0,0,0,0,0,0,0,0};
    short8 af0[4], af1[4];
#pragma unroll
    for (int i = 0; i < 4; ++i) {
      const int a = (wr * 64 + i * 16 + lm) * 8 + qsel;
      af0[i] = hasd ? *(const short8*)(A1 + a) : z8;
      af1[i] = hasd ? *(const short8*)(EZ + a) : z8;
    }
#pragma unroll
    for (int j2 = 0; j2 < 2; ++j2) {
      const int bb = (wc * 32 + j2 * 16 + lm) * 8 + qsel;
      const short8 bf0 = hasd ? *(const short8*)(SB + bb) : z8;
      const short8 bf1 = hasd ? *(const short8*)(ST + bb) : z8;
#pragma unroll
      for (int i = 0; i < 4; ++i) {
        acc0[i][j2] = __builtin_amdgcn_mfma_f32_16x16x32_bf16(af0[i], bf0, acc0[i][j2], 0, 0, 0);
        acc1[i][j2] = __builtin_amdgcn_mfma_f32_16x16x32_bf16(af1[i], bf1, acc1[i][j2], 0, 0, 0);
      }
    }
  }

  // ---- small reductions (negsum/ppsum gated to eh==0; segsum e-disjoint) ----
  __syncthreads();
  float* fr = (float*)lds;                       // 4608 floats used <= 5120
#pragma unroll
  for (int j = 0; j < 4; ++j) {
    fr[w * 256 + l + 64 * j] = accN[j];
    fr[2048 + w * 256 + l + 64 * j] = accP[j];
  }
  fr[4096 + w * 64 + l] = accS;
  __syncthreads();
  if (t < 256) {
    float sn = 0.f, sq = 0.f;
#pragma unroll
    for (int k = 0; k < 8; ++k) { sn += fr[k * 256 + t]; sq += fr[2048 + k * 256 + t]; }
    if (eh == 0) {
      atomicAdd(&negsum[b * 256 + t], sn);
      atomicAdd(&ppsum[b * 256 + t], sq);
    }
  } else if (t < 320) {
    const int e = t - 256;
    float ss = 0.f;
#pragma unroll
    for (int k = 0; k < 8; ++k) ss += fr[4096 + k * 64 + e];
    atomicAdd(&segsum[b * 128 + eh * 64 + e], ss);
  }
  cnt = wsum(cnt);
  if (l == 0) atomicAdd(&nnzb[b], cnt);

  // ---- split-K partials: two eh blocks fill disjoint e-columns of one slice ----
  if constexpr (DIRECT) {
    float* p0 = part + ((size_t)(ks * 8 + b) * 2) * 32768;
    float* p1 = p0 + 32768;
#pragma unroll
    for (int i = 0; i < 4; ++i)
#pragma unroll
      for (int r = 0; r < 4; ++r) {
        const int q = wr * 64 + i * 16 + quad * 4 + r;
#pragma unroll
        for (int j2 = 0; j2 < 2; ++j2) {
          const int eg = eh * 64 + wc * 32 + j2 * 16 + lm;
          p0[q * 128 + eg] = acc0[i][j2][r];
          p1[q * 128 + eg] = acc1[i][j2][r];
        }
      }
  } else {
    float* p0 = part + (size_t)b * 32768;
    float* p1 = part + (size_t)(8 + b) * 32768;
#pragma unroll
    for (int i = 0; i < 4; ++i)
#pragma unroll
      for (int r = 0; r < 4; ++r) {
        const int q = wr * 64 + i * 16 + quad * 4 + r;
#pragma unroll
        for (int j2 = 0; j2 < 2; ++j2) {
          const int eg = eh * 64 + wc * 32 + j2 * 16 + lm;
          atomicAdd(&p0[q * 128 + eg], acc0[i][j2][r]);
          atomicAdd(&p1[q * 128 + eg], acc1[i][j2][r]);
        }
      }
  }
}

// ---------- epilogue: split-K reduce + all closed-form cost terms ----------
template<bool DIRECT>
__global__ __launch_bounds__(128) void epilogue(
    const float* __restrict__ part,
    const float* __restrict__ negsum, const float* __restrict__ ppsum,
    const float* __restrict__ segsum, const float* __restrict__ nnzb,
    const float* __restrict__ logits, const float* __restrict__ ppos,
    const float* __restrict__ chol, const float* __restrict__ tpos,
    const float* __restrict__ imgsz, float* __restrict__ out)
{
  const int bq = blockIdx.x;          // b*256 + q
  const int b = bq >> 8;
  const int e = threadIdx.x;
  const int qe = (bq & 255) * 128 + e;

  float g1, g2;
  if constexpr (DIRECT) {
    g1 = 0.f; g2 = 0.f;
#pragma unroll 8
    for (int ksi = 0; ksi < 32; ++ksi) {
      g1 += part[((size_t)(ksi * 8 + b) * 2) * 32768 + qe];
      g2 += part[((size_t)(ksi * 8 + b) * 2 + 1) * 32768 + qe];
    }
  } else {
    g1 = part[(size_t)b * 32768 + qe];
    g2 = part[(size_t)(8 + b) * 32768 + qe];
  }

  const float nnz = fmaxf(nnzb[b], 1.f);
  const float mask_cost = (negsum[bq] + g1) / nnz;
  const float dice = 1.f - (2.f * g2 + 1.f) / (ppsum[bq] + segsum[b * 128 + e] + 1.f);
  const float cls = softplus_f(-logits[bq]);
  const float px = ppos[bq * 2], py = ppos[bq * 2 + 1];
  const float tx = tpos[(b * 128 + e) * 2], ty = tpos[(b * 128 + e) * 2 + 1];
  const float dx = px - tx, dy = py - ty;
  const float ax = fabsf(dx), ay = fabsf(dy);
  const float hx = (ax < 1.f) ? 0.5f * dx * dx : ax - 0.5f;
  const float hy = (ay < 1.f) ? 0.5f * dy * dy : ay - 0.5f;
  const float huber = 0.5f * (hx + hy);
  const float sx = imgsz[b * 2], sy = imgsz[b * 2 + 1];
  const float L00 = chol[bq * 4 + 0], L10 = chol[bq * 4 + 2], L11 = chol[bq * 4 + 3];
  const float d0 = (tx - px) * sx, d1 = (ty - py) * sy;
  const float z0 = d0 / L00;
  const float z1 = (d1 - L10 * z0) / L11;
  const float nll = 0.5f * (z0 * z0 + z1 * z1) + 1.8378770664093453f + __logf(L00) + __logf(L11);
  const float lik = 1.f - __expf(-nll);
  out[bq * 128 + e] = 2.f * cls + 5.f * mask_cost + 5.f * dice + huber + 0.5f * nll + 0.5f * lik;
}

// ---------- launcher ----------
extern "C" void kernel_launch(void* const* d_in, const int* in_sizes, int n_in,
                              void* d_out, int out_size, void* d_ws, size_t ws_size,
                              hipStream_t stream)
{
  (void)in_sizes; (void)n_in; (void)out_size;
  const float* logits = (const float*)d_in[0];
  const float* mlv    = (const float*)d_in[1];
  const int*   mask   = (const int*)d_in[2];
  const float* seg    = (const float*)d_in[3];
  const float* ppos   = (const float*)d_in[4];
  const float* chol   = (const float*)d_in[5];
  const float* tpos   = (const float*)d_in[6];
  const float* imgsz  = (const float*)d_in[7];

  char* ws = (char*)d_ws;
  const size_t PART_DIRECT = 67108864ull;               // 32ks*8b*2g*32768*4B
  const size_t NEED = PART_DIRECT + 20512ull;

  if (ws_size >= NEED) {
    float* part   = (float*)ws;
    float* negsum = (float*)(ws + PART_DIRECT);
    float* ppsum  = (float*)(ws + PART_DIRECT + 8192);
    float* segsum = (float*)(ws + PART_DIRECT + 16384);
    float* nnzb   = (float*)(ws + PART_DIRECT + 20480);
    hipMemsetAsync(ws + PART_DIRECT, 0, 20512, stream);  // only the small sums
    fused_all<true><<<512, 512, 0, stream>>>(mlv, mask, seg, part, negsum, ppsum, segsum, nnzb);
    epilogue<true><<<2048, 128, 0, stream>>>(part, negsum, ppsum, segsum, nnzb,
                                             logits, ppos, chol, tpos, imgsz, (float*)d_out);
  } else {
    float* part   = (float*)(ws);                    // [2][8][256][128]
    float* negsum = (float*)(ws + 2097152);
    float* ppsum  = (float*)(ws + 2105344);
    float* segsum = (float*)(ws + 2113536);
    float* nnzb   = (float*)(ws + 2117632);
    hipMemsetAsync(ws, 0, 2117664, stream);
    fused_all<false><<<512, 512, 0, stream>>>(mlv, mask, seg, part, negsum, ppsum, segsum, nnzb);
    epilogue<false><<<2048, 128, 0, stream>>>(part, negsum, ppsum, segsum, nnzb,
                                              logits, ppos, chol, tpos, imgsz, (float*)d_out);
  }
}